// Round 1
// baseline (285.589 us; speedup 1.0000x reference)
//
#include <hip/hip_runtime.h>
#include <math.h>
#include <stdint.h>

#define B_ 4
#define S_ 1024
#define F_ 512    // W*DIM = HEADS*HD
#define HD 128

typedef __attribute__((ext_vector_type(8))) short short8;
typedef __attribute__((ext_vector_type(4))) float f32x4;
typedef __attribute__((ext_vector_type(4))) unsigned int u32x4;

__device__ __forceinline__ unsigned short f2bf(float f) {
    unsigned int u = __float_as_uint(f);
    u = (u + 0x7FFFu + ((u >> 16) & 1u)) >> 16;
    return (unsigned short)u;
}
__device__ __forceinline__ float bf2f(unsigned int s) {
    return __uint_as_float(s << 16);
}
__device__ __forceinline__ float rmax16(float v) {
    v = fmaxf(v, __shfl_xor(v, 1));
    v = fmaxf(v, __shfl_xor(v, 2));
    v = fmaxf(v, __shfl_xor(v, 4));
    v = fmaxf(v, __shfl_xor(v, 8));
    return v;
}
__device__ __forceinline__ float rsum16(float v) {
    v += __shfl_xor(v, 1);
    v += __shfl_xor(v, 2);
    v += __shfl_xor(v, 4);
    v += __shfl_xor(v, 8);
    return v;
}

// ---------------------------------------------------------------------------
// K2: QKV projection.  y_e[b,s,f] = (x^T[b,s,w,:] @ emb_e^T + s_vec)  (bf16)
//     f = w*64+c ; q pre-scaled by 1/sqrt(128).
// grid 512 = (b in 4) x (s-tile of 8, 128 tiles), block 256.
// x reads are wave-uniform float4 broadcasts (rows of the s-tile); emb rows
// live in registers per output channel (c = lane).
// ---------------------------------------------------------------------------
__global__ __launch_bounds__(256) void k_qkv(
    const float* __restrict__ x, const float* __restrict__ strength,
    const int* __restrict__ embed_id,
    const float* __restrict__ qw, const float* __restrict__ kw,
    const float* __restrict__ vw,
    const float* __restrict__ str_w, const float* __restrict__ str_b,
    unsigned short* __restrict__ yq, unsigned short* __restrict__ yk,
    unsigned short* __restrict__ yv)
{
    __shared__ float part_s[4][64];
    __shared__ float sv_s[64];
    const int tid = threadIdx.x;
    const int b  = blockIdx.x >> 7;
    const int s0 = (blockIdx.x & 127) * 8;
    const int c  = tid & 63;       // output channel
    const int pr = tid >> 6;       // wave index = row group

    // strength projection (redundant per block, tiny)
    {
        float acc = 0.f;
        const float* wrow = str_w + c * 512 + pr * 128;
        const float* st   = strength + pr * 128;
        #pragma unroll 8
        for (int j = 0; j < 128; ++j) acc += st[j] * wrow[j];
        part_s[pr][c] = acc;
    }
    __syncthreads();
    if (pr == 0)
        sv_s[c] = part_s[0][c] + part_s[1][c] + part_s[2][c] + part_s[3][c] + str_b[c];
    __syncthreads();

    const int id = embed_id[0];
    const float* eq = qw + id * 4096;
    const float* ek = kw + id * 4096;
    const float* ev = vw + id * 4096;
    const float* xb = x + b * (64 * S_ * 8) + s0 * 8;
    const float SCALE = 0.08838834764831845f;  // 1/sqrt(128)
    const float sv = sv_s[c];

    #pragma unroll
    for (int i = 0; i < 4; ++i) {
        const int r0 = pr * 16 + i * 4;   // rows r0..r0+3 of the 64-row tile
        float aq[4], ak[4], av[4];
        #pragma unroll
        for (int rr = 0; rr < 4; ++rr) { aq[rr] = sv; ak[rr] = sv; av[rr] = sv; }
        #pragma unroll
        for (int half = 0; half < 2; ++half) {
            float eqr[32], ekr[32], evr[32];
            #pragma unroll
            for (int j4 = 0; j4 < 8; ++j4) {
                f32x4 tq = *(const f32x4*)(eq + c * 64 + half * 32 + j4 * 4);
                f32x4 tk = *(const f32x4*)(ek + c * 64 + half * 32 + j4 * 4);
                f32x4 tv = *(const f32x4*)(ev + c * 64 + half * 32 + j4 * 4);
                #pragma unroll
                for (int jj = 0; jj < 4; ++jj) {
                    eqr[j4 * 4 + jj] = tq[jj];
                    ekr[j4 * 4 + jj] = tk[jj];
                    evr[j4 * 4 + jj] = tv[jj];
                }
            }
            #pragma unroll
            for (int j = 0; j < 32; ++j) {
                // wave-uniform broadcast load: 4 consecutive (s,w) rows, channel j
                f32x4 x4 = *(const f32x4*)(xb + (half * 32 + j) * (S_ * 8) + r0);
                #pragma unroll
                for (int rr = 0; rr < 4; ++rr) {
                    aq[rr] += x4[rr] * eqr[j];
                    ak[rr] += x4[rr] * ekr[j];
                    av[rr] += x4[rr] * evr[j];
                }
            }
        }
        #pragma unroll
        for (int rr = 0; rr < 4; ++rr) {
            const int r = r0 + rr;
            const int base = (b * S_ + s0 + (r >> 3)) * F_ + (r & 7) * 64 + c;
            yq[base] = f2bf(aq[rr] * SCALE);
            yk[base] = f2bf(ak[rr]);
            yv[base] = f2bf(av[rr]);
        }
    }
}

// ---------------------------------------------------------------------------
// K2b: transpose V -> yvT[bh][d][t]  (bf16), 64x64 tiles through LDS.
// grid 512 = 16 bh x 2 d-tiles x 16 t-tiles, block 256.
// ---------------------------------------------------------------------------
__global__ __launch_bounds__(256) void k_vtrans(
    const unsigned short* __restrict__ yv, unsigned short* __restrict__ yvT)
{
    __shared__ unsigned short t_s[64 * 66];
    const int blk = blockIdx.x;
    const int bh = blk >> 5;
    const int dt = (blk >> 4) & 1;
    const int tt = blk & 15;
    const int b = bh >> 2, h = bh & 3;
    const int t0 = tt * 64, d0 = dt * 64;
    const unsigned int* src = (const unsigned int*)yv;
    for (int p = 0; p < 8; ++p) {
        int flat = p * 256 + threadIdx.x;
        int tr = flat >> 5, dp = flat & 31;
        unsigned int u = src[(b * S_ + t0 + tr) * 256 + (h * HD + d0) / 2 + dp];
        t_s[(2 * dp) * 66 + tr]     = (unsigned short)(u & 0xFFFFu);
        t_s[(2 * dp + 1) * 66 + tr] = (unsigned short)(u >> 16);
    }
    __syncthreads();
    unsigned int* dst = (unsigned int*)yvT;
    for (int p = 0; p < 8; ++p) {
        int flat = p * 256 + threadIdx.x;
        int dr = flat >> 5, tp = flat & 31;
        unsigned int lo = t_s[dr * 66 + 2 * tp];
        unsigned int hi = t_s[dr * 66 + 2 * tp + 1];
        dst[(bh * HD + d0 + dr) * (S_ / 2) + t0 / 2 + tp] = lo | (hi << 16);
    }
}

// ---------------------------------------------------------------------------
// K5: fused flash attention + pos-attention (rank-1 vbar) + gate combine.
// grid 512 = (bh in 16) x (q-tile of 32 rows, 32 tiles). block 256 (4 waves).
// S-phase: wave w owns t-columns 16w..16w+15 of the 64-wide tile.
// PV-phase: wave w owns d-slice 32w..32w+31.
// Cross-wave softmax stats (33 rows: 32 q-rows + pos-row) in LDS.
// Writes Y (pre-out-projection) into d_out.
// ---------------------------------------------------------------------------
__global__ __launch_bounds__(256, 2) void k_attn(
    const unsigned short* __restrict__ yq, const unsigned short* __restrict__ yk,
    const unsigned short* __restrict__ yvT,
    const float* __restrict__ pos,
    const float* __restrict__ pw1, const float* __restrict__ pb1,
    const float* __restrict__ pw2, const float* __restrict__ pb2,
    const float* __restrict__ head_w, const float* __restrict__ gate,
    float* __restrict__ out)
{
    __shared__ __align__(16) unsigned short p_s[32 * 72];
    __shared__ __align__(16) float p32_s[64];
    __shared__ float pmax_s[4][33], psum_s[4][33];
    __shared__ float m_s[33], l_s[33], alpha_s[33];

    const int tid  = threadIdx.x;
    const int w    = tid >> 6;
    const int lane = tid & 63;
    const int quad = lane >> 4;
    const int l15  = lane & 15;
    const int bh = blockIdx.x & 15, qt = blockIdx.x >> 4;
    const int b = bh >> 2, h = bh & 3;
    const int s0 = qt * 32;
    const int d0 = w * 32;

    if (tid < 33) {
        m_s[tid] = -INFINITY; l_s[tid] = 0.f; alpha_s[tid] = 0.f;
        #pragma unroll
        for (int ww = 0; ww < 4; ++ww) psum_s[ww][tid] = 0.f;
    }

    // pos-MLP weights (wave-uniform)
    float w1_[9], b1_[3], w2_[24], b2_[8], hw_[8];
    #pragma unroll
    for (int i = 0; i < 9; ++i)  w1_[i] = pw1[i];
    #pragma unroll
    for (int i = 0; i < 3; ++i)  b1_[i] = pb1[i];
    #pragma unroll
    for (int i = 0; i < 24; ++i) w2_[i] = pw2[i];
    #pragma unroll
    for (int i = 0; i < 8; ++i)  b2_[i] = pb2[i];
    #pragma unroll
    for (int i = 0; i < 8; ++i)  hw_[i] = head_w[h * 8 + i];

    // Q fragments, register-resident for the whole block (A-layout).
    u32x4 qf[2][4];
    #pragma unroll
    for (int mt = 0; mt < 2; ++mt)
        #pragma unroll
        for (int kc = 0; kc < 4; ++kc)
            qf[mt][kc] = *(const u32x4*)(yq +
                (size_t)(b * S_ + s0 + mt * 16 + l15) * F_ + h * HD + kc * 32 + quad * 8);

    f32x4 o[2][2] = {};
    float vnum[2] = {0.f, 0.f};
    __syncthreads();

    for (int tt = 0; tt < 16; ++tt) {
        const int t0 = tt * 64;
        const int tcol = t0 + w * 16 + l15;

        // ---- S = Q K^T (scale folded into q) ----
        u32x4 kf[4];
        #pragma unroll
        for (int kc = 0; kc < 4; ++kc)
            kf[kc] = *(const u32x4*)(yk +
                (size_t)(b * S_ + tcol) * F_ + h * HD + kc * 32 + quad * 8);
        f32x4 sacc[2] = {};
        #pragma unroll
        for (int mt = 0; mt < 2; ++mt)
            #pragma unroll
            for (int kc = 0; kc < 4; ++kc)
                sacc[mt] = __builtin_amdgcn_mfma_f32_16x16x32_bf16(
                    __builtin_bit_cast(short8, qf[mt][kc]),
                    __builtin_bit_cast(short8, kf[kc]), sacc[mt], 0, 0, 0);

        // ---- pos logit for this column: s32 = -(ph . head_w[h]) ----
        float p0c = pos[(b * S_ + tcol) * 3 + 0];
        float p1c = pos[(b * S_ + tcol) * 3 + 1];
        float p2c = pos[(b * S_ + tcol) * 3 + 2];
        float h0 = fmaxf(0.f, p0c * w1_[0] + p1c * w1_[1] + p2c * w1_[2] + b1_[0]);
        float h1 = fmaxf(0.f, p0c * w1_[3] + p1c * w1_[4] + p2c * w1_[5] + b1_[1]);
        float h2 = fmaxf(0.f, p0c * w1_[6] + p1c * w1_[7] + p2c * w1_[8] + b1_[2]);
        float A = 0.f;
        #pragma unroll
        for (int o8 = 0; o8 < 8; ++o8) {
            float ph = h0 * w2_[o8 * 3] + h1 * w2_[o8 * 3 + 1] + h2 * w2_[o8 * 3 + 2] + b2_[o8];
            A += ph * hw_[o8];
        }
        const float s32 = -A;

        // ---- per-wave partial row maxima ----
        #pragma unroll
        for (int mt = 0; mt < 2; ++mt)
            #pragma unroll
            for (int r = 0; r < 4; ++r) {
                float m = rmax16(sacc[mt][r]);
                if (l15 == 0) pmax_s[w][mt * 16 + quad * 4 + r] = m;
            }
        {
            float m32 = rmax16(s32);
            if (lane == 0) pmax_s[w][32] = m32;
        }
        __syncthreads();

        // ---- combine stats (+ fold previous tile's row-sums into l) ----
        if (tid < 33) {
            float ps = psum_s[0][tid] + psum_s[1][tid] + psum_s[2][tid] + psum_s[3][tid];
            l_s[tid] = alpha_s[tid] * l_s[tid] + ps;
            float pmx = fmaxf(fmaxf(pmax_s[0][tid], pmax_s[1][tid]),
                              fmaxf(pmax_s[2][tid], pmax_s[3][tid]));
            float mo = m_s[tid];
            float mn = fmaxf(mo, pmx);
            alpha_s[tid] = __expf(mo - mn);
            m_s[tid] = mn;
        }
        __syncthreads();

        // ---- P = exp(S - m), write to LDS (bf16), rescale O, partial sums ----
        #pragma unroll
        for (int mt = 0; mt < 2; ++mt)
            #pragma unroll
            for (int r = 0; r < 4; ++r) {
                const int row = mt * 16 + quad * 4 + r;
                const float mn = m_s[row];
                const float al = alpha_s[row];
                float p = __expf(sacc[mt][r] - mn);
                o[mt][0][r] *= al;
                o[mt][1][r] *= al;
                p_s[row * 72 + w * 16 + l15] = f2bf(p);
                float ssum = rsum16(p);
                if (l15 == 0) psum_s[w][row] = ssum;
            }
        {
            const float mn = m_s[32];
            const float al = alpha_s[32];
            float p = __expf(s32 - mn);
            vnum[0] *= al; vnum[1] *= al;
            if (quad == 0) p32_s[w * 16 + l15] = p;
            float ssum = rsum16(p);
            if (lane == 0) psum_s[w][32] = ssum;
        }
        __syncthreads();

        // ---- PV: O += P V  (P from LDS A-layout, V from transposed global) ----
        u32x4 pA[2][2];
        #pragma unroll
        for (int mt = 0; mt < 2; ++mt)
            #pragma unroll
            for (int kt = 0; kt < 2; ++kt)
                pA[mt][kt] = *(const u32x4*)&p_s[(mt * 16 + l15) * 72 + kt * 32 + quad * 8];
        u32x4 vB[2][2];
        #pragma unroll
        for (int nt = 0; nt < 2; ++nt)
            #pragma unroll
            for (int kt = 0; kt < 2; ++kt)
                vB[nt][kt] = *(const u32x4*)(yvT +
                    (size_t)(bh * HD + d0 + nt * 16 + l15) * S_ + t0 + kt * 32 + quad * 8);
        #pragma unroll
        for (int mt = 0; mt < 2; ++mt)
            #pragma unroll
            for (int nt = 0; nt < 2; ++nt)
                #pragma unroll
                for (int kt = 0; kt < 2; ++kt)
                    o[mt][nt] = __builtin_amdgcn_mfma_f32_16x16x32_bf16(
                        __builtin_bit_cast(short8, pA[mt][kt]),
                        __builtin_bit_cast(short8, vB[nt][kt]), o[mt][nt], 0, 0, 0);

        // ---- vbar numerator (pos branch) ----
        #pragma unroll
        for (int kt = 0; kt < 2; ++kt) {
            f32x4 pa = *(const f32x4*)&p32_s[kt * 32 + quad * 8];
            f32x4 pb = *(const f32x4*)&p32_s[kt * 32 + quad * 8 + 4];
            #pragma unroll
            for (int nt = 0; nt < 2; ++nt) {
                u32x4 v = vB[nt][kt];
                vnum[nt] += pa[0] * bf2f(v[0] & 0xFFFFu) + pa[1] * bf2f(v[0] >> 16)
                          + pa[2] * bf2f(v[1] & 0xFFFFu) + pa[3] * bf2f(v[1] >> 16)
                          + pb[0] * bf2f(v[2] & 0xFFFFu) + pb[1] * bf2f(v[2] >> 16)
                          + pb[2] * bf2f(v[3] & 0xFFFFu) + pb[3] * bf2f(v[3] >> 16);
            }
        }
    }

    // ---- epilogue: final l fold, normalize, gate combine, write Y ----
    __syncthreads();
    if (tid < 33) {
        float ps = psum_s[0][tid] + psum_s[1][tid] + psum_s[2][tid] + psum_s[3][tid];
        l_s[tid] = alpha_s[tid] * l_s[tid] + ps;
    }
    __syncthreads();

    const float gf = 1.f / (1.f + __expf(-gate[h]));
    float vbar[2];
    #pragma unroll
    for (int nt = 0; nt < 2; ++nt) {
        float v = vnum[nt];
        v += __shfl_xor(v, 16);
        v += __shfl_xor(v, 32);
        vbar[nt] = v / l_s[32];
    }
    #pragma unroll
    for (int mt = 0; mt < 2; ++mt)
        #pragma unroll
        for (int r = 0; r < 4; ++r) {
            const int row = mt * 16 + quad * 4 + r;
            const float invl = 1.f / l_s[row];
            #pragma unroll
            for (int nt = 0; nt < 2; ++nt) {
                float val = o[mt][nt][r] * invl;
                float y = (1.f - gf) * val + gf * vbar[nt];
                out[(size_t)(b * S_ + s0 + row) * F_ + h * HD + d0 + nt * 16 + l15] = y;
            }
        }
}

// ---------------------------------------------------------------------------
// K6: output projection, in-place on d_out.  out_row = Y_row @ out_w^T + out_b
// per (b,s,w) 64-row. grid 1024 x 256; wave-uniform row loads, weights in regs.
// ---------------------------------------------------------------------------
__global__ __launch_bounds__(256) void k_oproj(
    float* __restrict__ out, const float* __restrict__ ow,
    const float* __restrict__ ob)
{
    const int tid = threadIdx.x;
    const int wv = tid >> 6, lane = tid & 63;
    float wr[64];
    #pragma unroll
    for (int j4 = 0; j4 < 16; ++j4) {
        f32x4 t = *(const f32x4*)(ow + lane * 64 + j4 * 4);
        wr[j4 * 4] = t[0]; wr[j4 * 4 + 1] = t[1];
        wr[j4 * 4 + 2] = t[2]; wr[j4 * 4 + 3] = t[3];
    }
    const float bias = ob[lane];
    const int row0 = blockIdx.x * 32 + wv * 8;
    for (int rr = 0; rr < 8; ++rr) {
        const float* yrow = out + (size_t)(row0 + rr) * 64;  // wave-uniform
        float acc = bias;
        #pragma unroll
        for (int j4 = 0; j4 < 16; ++j4) {
            f32x4 y4 = *(const f32x4*)(yrow + j4 * 4);
            acc += y4[0] * wr[j4 * 4] + y4[1] * wr[j4 * 4 + 1]
                 + y4[2] * wr[j4 * 4 + 2] + y4[3] * wr[j4 * 4 + 3];
        }
        out[(size_t)(row0 + rr) * 64 + lane] = acc;  // all lanes read before store
    }
}

extern "C" void kernel_launch(void* const* d_in, const int* in_sizes, int n_in,
                              void* d_out, int out_size, void* d_ws, size_t ws_size,
                              hipStream_t stream) {
    (void)in_sizes; (void)n_in; (void)out_size; (void)ws_size;
    const float* x        = (const float*)d_in[0];
    const float* pos      = (const float*)d_in[1];
    const float* strength = (const float*)d_in[2];
    const int*   embed_id = (const int*)d_in[3];
    const float* qw       = (const float*)d_in[4];
    const float* kw       = (const float*)d_in[5];
    const float* vw       = (const float*)d_in[6];
    const float* pw1      = (const float*)d_in[7];
    const float* pb1      = (const float*)d_in[8];
    const float* pw2      = (const float*)d_in[9];
    const float* pb2      = (const float*)d_in[10];
    const float* head_w   = (const float*)d_in[11];
    const float* gate     = (const float*)d_in[13];
    const float* out_w    = (const float*)d_in[14];
    const float* out_b    = (const float*)d_in[15];
    const float* str_w    = (const float*)d_in[16];
    const float* str_b    = (const float*)d_in[17];
    float* out = (float*)d_out;

    unsigned short* yq  = (unsigned short*)d_ws;
    unsigned short* yk  = yq + 2097152;
    unsigned short* yv  = yk + 2097152;
    unsigned short* yvT = yv + 2097152;   // total 16 MiB of workspace

    k_qkv<<<512, 256, 0, stream>>>(x, strength, embed_id, qw, kw, vw,
                                   str_w, str_b, yq, yk, yv);
    k_vtrans<<<512, 256, 0, stream>>>(yv, yvT);
    k_attn<<<512, 256, 0, stream>>>(yq, yk, yvT, pos, pw1, pb1, pw2, pb2,
                                    head_w, gate, out);
    k_oproj<<<1024, 256, 0, stream>>>(out, out_w, out_b);
}

// Round 2
// 225.785 us; speedup vs baseline: 1.2649x; 1.2649x over previous
//
#include <hip/hip_runtime.h>
#include <math.h>
#include <stdint.h>

#define B_ 4
#define S_ 1024
#define F_ 512    // W*DIM = HEADS*HD
#define HD 128

typedef __attribute__((ext_vector_type(8))) short short8;
typedef __attribute__((ext_vector_type(4))) float f32x4;
typedef __attribute__((ext_vector_type(4))) unsigned int u32x4;
typedef __attribute__((ext_vector_type(2))) unsigned int u32x2;

__device__ __forceinline__ unsigned short f2bf(float f) {
    unsigned int u = __float_as_uint(f);
    u = (u + 0x7FFFu + ((u >> 16) & 1u)) >> 16;
    return (unsigned short)u;
}
__device__ __forceinline__ float bf2f(unsigned int s) {
    return __uint_as_float(s << 16);
}
__device__ __forceinline__ float rmax16(float v) {
    v = fmaxf(v, __shfl_xor(v, 1));
    v = fmaxf(v, __shfl_xor(v, 2));
    v = fmaxf(v, __shfl_xor(v, 4));
    v = fmaxf(v, __shfl_xor(v, 8));
    return v;
}
__device__ __forceinline__ float rsum16(float v) {
    v += __shfl_xor(v, 1);
    v += __shfl_xor(v, 2);
    v += __shfl_xor(v, 4);
    v += __shfl_xor(v, 8);
    return v;
}

// ---------------------------------------------------------------------------
// K0: strength projection, once (1 block).  sv[c] = str_w[c,:]@strength + str_b
// ---------------------------------------------------------------------------
__global__ __launch_bounds__(256) void k_sv(
    const float* __restrict__ strength, const float* __restrict__ str_w,
    const float* __restrict__ str_b, float* __restrict__ sv)
{
    __shared__ float part_s[4][64];
    const int c = threadIdx.x & 63, pr = threadIdx.x >> 6;
    const float* wrow = str_w + c * 512 + pr * 128;
    const float* st   = strength + pr * 128;
    float acc = 0.f;
    #pragma unroll
    for (int j4 = 0; j4 < 32; ++j4) {
        f32x4 wv = *(const f32x4*)(wrow + j4 * 4);
        f32x4 s4 = *(const f32x4*)(st + j4 * 4);
        acc += wv[0] * s4[0] + wv[1] * s4[1] + wv[2] * s4[2] + wv[3] * s4[3];
    }
    part_s[pr][c] = acc;
    __syncthreads();
    if (threadIdx.x < 64)
        sv[threadIdx.x] = part_s[0][threadIdx.x] + part_s[1][threadIdx.x]
                        + part_s[2][threadIdx.x] + part_s[3][threadIdx.x]
                        + str_b[threadIdx.x];
}

// ---------------------------------------------------------------------------
// K1: QKV projection as MFMA GEMM (no LDS, no transpose).
//   outT[c'][row] = emb[c'][:] . xt[row][:] + sv[c']
//   A = emb (m=c', k=c, contiguous loads), B = x^T (n=row: lane-indexed rows
//   make x's [c][row] layout load coalesced as the B fragment directly).
//   Split-bf16 (hi/lo) x and emb -> 3 MFMA terms == fp32 accuracy.
//   Wave handles 16 rows; block 64 rows; grid 512.
// ---------------------------------------------------------------------------
__global__ __launch_bounds__(256) void k_qkv(
    const float* __restrict__ x, const int* __restrict__ embed_id,
    const float* __restrict__ qw, const float* __restrict__ kw,
    const float* __restrict__ vw, const float* __restrict__ sv,
    unsigned short* __restrict__ yq, unsigned short* __restrict__ yk,
    unsigned short* __restrict__ yv)
{
    const int tid  = threadIdx.x;
    const int wv   = tid >> 6;
    const int lane = tid & 63;
    const int quad = lane >> 4;
    const int l15  = lane & 15;
    const int r0   = blockIdx.x * 64 + wv * 16;   // 16 rows for this wave
    const int b    = r0 >> 13;
    const int rloc = (r0 & 8191) + l15;           // row within batch
    const float* xb = x + (size_t)b * 524288;
    const int id = embed_id[0];

    // B fragments (x^T), hi/lo split.  B[n=l15][k=quad*8+j]
    u32x4 bhi[2], blo[2];
    #pragma unroll
    for (int kc = 0; kc < 2; ++kc) {
        float xv[8];
        #pragma unroll
        for (int j = 0; j < 8; ++j)
            xv[j] = xb[(kc * 32 + quad * 8 + j) * 8192 + rloc];
        #pragma unroll
        for (int p = 0; p < 4; ++p) {
            unsigned int h0 = f2bf(xv[2 * p]), h1 = f2bf(xv[2 * p + 1]);
            float l0 = xv[2 * p] - bf2f(h0), l1 = xv[2 * p + 1] - bf2f(h1);
            bhi[kc][p] = h0 | (h1 << 16);
            blo[kc][p] = (unsigned int)f2bf(l0) | ((unsigned int)f2bf(l1) << 16);
        }
    }

    // strength values for this lane's D elements: c' = mt*16 + quad*4 + r
    f32x4 svr[4];
    #pragma unroll
    for (int mt = 0; mt < 4; ++mt)
        svr[mt] = *(const f32x4*)(sv + mt * 16 + quad * 4);

    const float SCALE = 0.08838834764831845f;  // 1/sqrt(128)

    for (int mat = 0; mat < 3; ++mat) {
        const float* em = (mat == 0 ? qw : mat == 1 ? kw : vw) + id * 4096;
        // A fragments: A[m=l15][k=quad*8+j], m-tile mt -> c' = mt*16+l15
        u32x4 ahi[4][2], alo[4][2];
        #pragma unroll
        for (int mt = 0; mt < 4; ++mt)
            #pragma unroll
            for (int kc = 0; kc < 2; ++kc) {
                const float* src = em + (mt * 16 + l15) * 64 + kc * 32 + quad * 8;
                f32x4 e0 = *(const f32x4*)src;
                f32x4 e1 = *(const f32x4*)(src + 4);
                float ev[8] = {e0[0], e0[1], e0[2], e0[3], e1[0], e1[1], e1[2], e1[3]};
                #pragma unroll
                for (int p = 0; p < 4; ++p) {
                    unsigned int h0 = f2bf(ev[2 * p]), h1 = f2bf(ev[2 * p + 1]);
                    float l0 = ev[2 * p] - bf2f(h0), l1 = ev[2 * p + 1] - bf2f(h1);
                    ahi[mt][kc][p] = h0 | (h1 << 16);
                    alo[mt][kc][p] = (unsigned int)f2bf(l0) | ((unsigned int)f2bf(l1) << 16);
                }
            }

        f32x4 acc[4] = {};
        #pragma unroll
        for (int kc = 0; kc < 2; ++kc)
            #pragma unroll
            for (int mt = 0; mt < 4; ++mt) {
                acc[mt] = __builtin_amdgcn_mfma_f32_16x16x32_bf16(
                    __builtin_bit_cast(short8, ahi[mt][kc]),
                    __builtin_bit_cast(short8, bhi[kc]), acc[mt], 0, 0, 0);
                acc[mt] = __builtin_amdgcn_mfma_f32_16x16x32_bf16(
                    __builtin_bit_cast(short8, ahi[mt][kc]),
                    __builtin_bit_cast(short8, blo[kc]), acc[mt], 0, 0, 0);
                acc[mt] = __builtin_amdgcn_mfma_f32_16x16x32_bf16(
                    __builtin_bit_cast(short8, alo[mt][kc]),
                    __builtin_bit_cast(short8, bhi[kc]), acc[mt], 0, 0, 0);
            }

        // D[col=l15 -> row r0+l15][row=quad*4+r -> c'=mt*16+quad*4+r]
        unsigned short* y = (mat == 0 ? yq : mat == 1 ? yk : yv);
        #pragma unroll
        for (int mt = 0; mt < 4; ++mt) {
            float v0 = acc[mt][0] + svr[mt][0];
            float v1 = acc[mt][1] + svr[mt][1];
            float v2 = acc[mt][2] + svr[mt][2];
            float v3 = acc[mt][3] + svr[mt][3];
            if (mat == 0) { v0 *= SCALE; v1 *= SCALE; v2 *= SCALE; v3 *= SCALE; }
            u32x2 pk;
            pk[0] = (unsigned int)f2bf(v0) | ((unsigned int)f2bf(v1) << 16);
            pk[1] = (unsigned int)f2bf(v2) | ((unsigned int)f2bf(v3) << 16);
            *(u32x2*)(y + (size_t)(r0 + l15) * 64 + mt * 16 + quad * 4) = pk;
        }
    }
}

// ---------------------------------------------------------------------------
// K2b: transpose V -> yvT[bh][d][t]  (bf16), 64x64 tiles through LDS.
// grid 512 = 16 bh x 2 d-tiles x 16 t-tiles, block 256.
// ---------------------------------------------------------------------------
__global__ __launch_bounds__(256) void k_vtrans(
    const unsigned short* __restrict__ yv, unsigned short* __restrict__ yvT)
{
    __shared__ unsigned short t_s[64 * 66];
    const int blk = blockIdx.x;
    const int bh = blk >> 5;
    const int dt = (blk >> 4) & 1;
    const int tt = blk & 15;
    const int b = bh >> 2, h = bh & 3;
    const int t0 = tt * 64, d0 = dt * 64;
    const unsigned int* src = (const unsigned int*)yv;
    for (int p = 0; p < 8; ++p) {
        int flat = p * 256 + threadIdx.x;
        int tr = flat >> 5, dp = flat & 31;
        unsigned int u = src[(b * S_ + t0 + tr) * 256 + (h * HD + d0) / 2 + dp];
        t_s[(2 * dp) * 66 + tr]     = (unsigned short)(u & 0xFFFFu);
        t_s[(2 * dp + 1) * 66 + tr] = (unsigned short)(u >> 16);
    }
    __syncthreads();
    unsigned int* dst = (unsigned int*)yvT;
    for (int p = 0; p < 8; ++p) {
        int flat = p * 256 + threadIdx.x;
        int dr = flat >> 5, tp = flat & 31;
        unsigned int lo = t_s[dr * 66 + 2 * tp];
        unsigned int hi = t_s[dr * 66 + 2 * tp + 1];
        dst[(bh * HD + d0 + dr) * (S_ / 2) + t0 / 2 + tp] = lo | (hi << 16);
    }
}

// ---------------------------------------------------------------------------
// K5: fused flash attention + pos-attention (rank-1 vbar) + gate combine.
// grid 512 = (bh in 16) x (q-tile of 32 rows, 32 tiles). block 256 (4 waves).
// ---------------------------------------------------------------------------
__global__ __launch_bounds__(256, 2) void k_attn(
    const unsigned short* __restrict__ yq, const unsigned short* __restrict__ yk,
    const unsigned short* __restrict__ yvT,
    const float* __restrict__ pos,
    const float* __restrict__ pw1, const float* __restrict__ pb1,
    const float* __restrict__ pw2, const float* __restrict__ pb2,
    const float* __restrict__ head_w, const float* __restrict__ gate,
    float* __restrict__ out)
{
    __shared__ __align__(16) unsigned short p_s[32 * 72];
    __shared__ __align__(16) float p32_s[64];
    __shared__ float pmax_s[4][33], psum_s[4][33];
    __shared__ float m_s[33], l_s[33], alpha_s[33];

    const int tid  = threadIdx.x;
    const int w    = tid >> 6;
    const int lane = tid & 63;
    const int quad = lane >> 4;
    const int l15  = lane & 15;
    const int bh = blockIdx.x & 15, qt = blockIdx.x >> 4;
    const int b = bh >> 2, h = bh & 3;
    const int s0 = qt * 32;
    const int d0 = w * 32;

    if (tid < 33) {
        m_s[tid] = -INFINITY; l_s[tid] = 0.f; alpha_s[tid] = 0.f;
        #pragma unroll
        for (int ww = 0; ww < 4; ++ww) psum_s[ww][tid] = 0.f;
    }

    // pos-MLP weights (wave-uniform)
    float w1_[9], b1_[3], w2_[24], b2_[8], hw_[8];
    #pragma unroll
    for (int i = 0; i < 9; ++i)  w1_[i] = pw1[i];
    #pragma unroll
    for (int i = 0; i < 3; ++i)  b1_[i] = pb1[i];
    #pragma unroll
    for (int i = 0; i < 24; ++i) w2_[i] = pw2[i];
    #pragma unroll
    for (int i = 0; i < 8; ++i)  b2_[i] = pb2[i];
    #pragma unroll
    for (int i = 0; i < 8; ++i)  hw_[i] = head_w[h * 8 + i];

    // Q fragments, register-resident for the whole block (A-layout).
    u32x4 qf[2][4];
    #pragma unroll
    for (int mt = 0; mt < 2; ++mt)
        #pragma unroll
        for (int kc = 0; kc < 4; ++kc)
            qf[mt][kc] = *(const u32x4*)(yq +
                (size_t)(b * S_ + s0 + mt * 16 + l15) * F_ + h * HD + kc * 32 + quad * 8);

    f32x4 o[2][2] = {};
    float vnum[2] = {0.f, 0.f};
    __syncthreads();

    for (int tt = 0; tt < 16; ++tt) {
        const int t0 = tt * 64;
        const int tcol = t0 + w * 16 + l15;

        // ---- S = Q K^T (scale folded into q) ----
        u32x4 kf[4];
        #pragma unroll
        for (int kc = 0; kc < 4; ++kc)
            kf[kc] = *(const u32x4*)(yk +
                (size_t)(b * S_ + tcol) * F_ + h * HD + kc * 32 + quad * 8);
        f32x4 sacc[2] = {};
        #pragma unroll
        for (int mt = 0; mt < 2; ++mt)
            #pragma unroll
            for (int kc = 0; kc < 4; ++kc)
                sacc[mt] = __builtin_amdgcn_mfma_f32_16x16x32_bf16(
                    __builtin_bit_cast(short8, qf[mt][kc]),
                    __builtin_bit_cast(short8, kf[kc]), sacc[mt], 0, 0, 0);

        // ---- pos logit for this column: s32 = -(ph . head_w[h]) ----
        float p0c = pos[(b * S_ + tcol) * 3 + 0];
        float p1c = pos[(b * S_ + tcol) * 3 + 1];
        float p2c = pos[(b * S_ + tcol) * 3 + 2];
        float h0 = fmaxf(0.f, p0c * w1_[0] + p1c * w1_[1] + p2c * w1_[2] + b1_[0]);
        float h1 = fmaxf(0.f, p0c * w1_[3] + p1c * w1_[4] + p2c * w1_[5] + b1_[1]);
        float h2 = fmaxf(0.f, p0c * w1_[6] + p1c * w1_[7] + p2c * w1_[8] + b1_[2]);
        float A = 0.f;
        #pragma unroll
        for (int o8 = 0; o8 < 8; ++o8) {
            float ph = h0 * w2_[o8 * 3] + h1 * w2_[o8 * 3 + 1] + h2 * w2_[o8 * 3 + 2] + b2_[o8];
            A += ph * hw_[o8];
        }
        const float s32 = -A;

        // ---- per-wave partial row maxima ----
        #pragma unroll
        for (int mt = 0; mt < 2; ++mt)
            #pragma unroll
            for (int r = 0; r < 4; ++r) {
                float m = rmax16(sacc[mt][r]);
                if (l15 == 0) pmax_s[w][mt * 16 + quad * 4 + r] = m;
            }
        {
            float m32 = rmax16(s32);
            if (lane == 0) pmax_s[w][32] = m32;
        }
        __syncthreads();

        // ---- combine stats (+ fold previous tile's row-sums into l) ----
        if (tid < 33) {
            float ps = psum_s[0][tid] + psum_s[1][tid] + psum_s[2][tid] + psum_s[3][tid];
            l_s[tid] = alpha_s[tid] * l_s[tid] + ps;
            float pmx = fmaxf(fmaxf(pmax_s[0][tid], pmax_s[1][tid]),
                              fmaxf(pmax_s[2][tid], pmax_s[3][tid]));
            float mo = m_s[tid];
            float mn = fmaxf(mo, pmx);
            alpha_s[tid] = __expf(mo - mn);
            m_s[tid] = mn;
        }
        __syncthreads();

        // ---- P = exp(S - m), write to LDS (bf16), rescale O, partial sums ----
        #pragma unroll
        for (int mt = 0; mt < 2; ++mt)
            #pragma unroll
            for (int r = 0; r < 4; ++r) {
                const int row = mt * 16 + quad * 4 + r;
                const float mn = m_s[row];
                const float al = alpha_s[row];
                float p = __expf(sacc[mt][r] - mn);
                o[mt][0][r] *= al;
                o[mt][1][r] *= al;
                p_s[row * 72 + w * 16 + l15] = f2bf(p);
                float ssum = rsum16(p);
                if (l15 == 0) psum_s[w][row] = ssum;
            }
        {
            const float mn = m_s[32];
            const float al = alpha_s[32];
            float p = __expf(s32 - mn);
            vnum[0] *= al; vnum[1] *= al;
            if (quad == 0) p32_s[w * 16 + l15] = p;
            float ssum = rsum16(p);
            if (lane == 0) psum_s[w][32] = ssum;
        }
        __syncthreads();

        // ---- PV: O += P V  (P from LDS A-layout, V from transposed global) ----
        u32x4 pA[2][2];
        #pragma unroll
        for (int mt = 0; mt < 2; ++mt)
            #pragma unroll
            for (int kt = 0; kt < 2; ++kt)
                pA[mt][kt] = *(const u32x4*)&p_s[(mt * 16 + l15) * 72 + kt * 32 + quad * 8];
        u32x4 vB[2][2];
        #pragma unroll
        for (int nt = 0; nt < 2; ++nt)
            #pragma unroll
            for (int kt = 0; kt < 2; ++kt)
                vB[nt][kt] = *(const u32x4*)(yvT +
                    (size_t)(bh * HD + d0 + nt * 16 + l15) * S_ + t0 + kt * 32 + quad * 8);
        #pragma unroll
        for (int mt = 0; mt < 2; ++mt)
            #pragma unroll
            for (int nt = 0; nt < 2; ++nt)
                #pragma unroll
                for (int kt = 0; kt < 2; ++kt)
                    o[mt][nt] = __builtin_amdgcn_mfma_f32_16x16x32_bf16(
                        __builtin_bit_cast(short8, pA[mt][kt]),
                        __builtin_bit_cast(short8, vB[nt][kt]), o[mt][nt], 0, 0, 0);

        // ---- vbar numerator (pos branch) ----
        #pragma unroll
        for (int kt = 0; kt < 2; ++kt) {
            f32x4 pa = *(const f32x4*)&p32_s[kt * 32 + quad * 8];
            f32x4 pb = *(const f32x4*)&p32_s[kt * 32 + quad * 8 + 4];
            #pragma unroll
            for (int nt = 0; nt < 2; ++nt) {
                u32x4 v = vB[nt][kt];
                vnum[nt] += pa[0] * bf2f(v[0] & 0xFFFFu) + pa[1] * bf2f(v[0] >> 16)
                          + pa[2] * bf2f(v[1] & 0xFFFFu) + pa[3] * bf2f(v[1] >> 16)
                          + pb[0] * bf2f(v[2] & 0xFFFFu) + pb[1] * bf2f(v[2] >> 16)
                          + pb[2] * bf2f(v[3] & 0xFFFFu) + pb[3] * bf2f(v[3] >> 16);
            }
        }
    }

    // ---- epilogue: final l fold, normalize, gate combine, write Y ----
    __syncthreads();
    if (tid < 33) {
        float ps = psum_s[0][tid] + psum_s[1][tid] + psum_s[2][tid] + psum_s[3][tid];
        l_s[tid] = alpha_s[tid] * l_s[tid] + ps;
    }
    __syncthreads();

    const float gf = 1.f / (1.f + __expf(-gate[h]));
    float vbar[2];
    #pragma unroll
    for (int nt = 0; nt < 2; ++nt) {
        float v = vnum[nt];
        v += __shfl_xor(v, 16);
        v += __shfl_xor(v, 32);
        vbar[nt] = v / l_s[32];
    }
    #pragma unroll
    for (int mt = 0; mt < 2; ++mt)
        #pragma unroll
        for (int r = 0; r < 4; ++r) {
            const int row = mt * 16 + quad * 4 + r;
            const float invl = 1.f / l_s[row];
            #pragma unroll
            for (int nt = 0; nt < 2; ++nt) {
                float val = o[mt][nt][r] * invl;
                float y = (1.f - gf) * val + gf * vbar[nt];
                out[(size_t)(b * S_ + s0 + row) * F_ + h * HD + d0 + nt * 16 + l15] = y;
            }
        }
}

// ---------------------------------------------------------------------------
// K6: output projection, in-place on d_out.
// ---------------------------------------------------------------------------
__global__ __launch_bounds__(256) void k_oproj(
    float* __restrict__ out, const float* __restrict__ ow,
    const float* __restrict__ ob)
{
    const int tid = threadIdx.x;
    const int wv = tid >> 6, lane = tid & 63;
    float wr[64];
    #pragma unroll
    for (int j4 = 0; j4 < 16; ++j4) {
        f32x4 t = *(const f32x4*)(ow + lane * 64 + j4 * 4);
        wr[j4 * 4] = t[0]; wr[j4 * 4 + 1] = t[1];
        wr[j4 * 4 + 2] = t[2]; wr[j4 * 4 + 3] = t[3];
    }
    const float bias = ob[lane];
    const int row0 = blockIdx.x * 32 + wv * 8;
    for (int rr = 0; rr < 8; ++rr) {
        const float* yrow = out + (size_t)(row0 + rr) * 64;  // wave-uniform
        float acc = bias;
        #pragma unroll
        for (int j4 = 0; j4 < 16; ++j4) {
            f32x4 y4 = *(const f32x4*)(yrow + j4 * 4);
            acc += y4[0] * wr[j4 * 4] + y4[1] * wr[j4 * 4 + 1]
                 + y4[2] * wr[j4 * 4 + 2] + y4[3] * wr[j4 * 4 + 3];
        }
        out[(size_t)(row0 + rr) * 64 + lane] = acc;  // all lanes read before store
    }
}

extern "C" void kernel_launch(void* const* d_in, const int* in_sizes, int n_in,
                              void* d_out, int out_size, void* d_ws, size_t ws_size,
                              hipStream_t stream) {
    (void)in_sizes; (void)n_in; (void)out_size; (void)ws_size;
    const float* x        = (const float*)d_in[0];
    const float* pos      = (const float*)d_in[1];
    const float* strength = (const float*)d_in[2];
    const int*   embed_id = (const int*)d_in[3];
    const float* qw       = (const float*)d_in[4];
    const float* kw       = (const float*)d_in[5];
    const float* vw       = (const float*)d_in[6];
    const float* pw1      = (const float*)d_in[7];
    const float* pb1      = (const float*)d_in[8];
    const float* pw2      = (const float*)d_in[9];
    const float* pb2      = (const float*)d_in[10];
    const float* head_w   = (const float*)d_in[11];
    const float* gate     = (const float*)d_in[13];
    const float* out_w    = (const float*)d_in[14];
    const float* out_b    = (const float*)d_in[15];
    const float* str_w    = (const float*)d_in[16];
    const float* str_b    = (const float*)d_in[17];
    float* out = (float*)d_out;

    unsigned short* yq  = (unsigned short*)d_ws;
    unsigned short* yk  = yq + 2097152;
    unsigned short* yv  = yk + 2097152;
    unsigned short* yvT = yv + 2097152;   // total 16 MiB of workspace
    // sv parks in the yvT region: consumed by k_qkv BEFORE k_vtrans writes yvT
    float* sv = (float*)yvT;

    k_sv<<<1, 256, 0, stream>>>(strength, str_w, str_b, sv);
    k_qkv<<<512, 256, 0, stream>>>(x, embed_id, qw, kw, vw, sv, yq, yk, yv);
    k_vtrans<<<512, 256, 0, stream>>>(yv, yvT);
    k_attn<<<512, 256, 0, stream>>>(yq, yk, yvT, pos, pw1, pb1, pw2, pb2,
                                    head_w, gate, out);
    k_oproj<<<1024, 256, 0, stream>>>(out, out_w, out_b);
}

// Round 3
// 200.373 us; speedup vs baseline: 1.4253x; 1.1268x over previous
//
#include <hip/hip_runtime.h>
#include <math.h>
#include <stdint.h>

#define B_ 4
#define S_ 1024
#define F_ 512    // W*DIM = HEADS*HD
#define HD 128

typedef __attribute__((ext_vector_type(8))) short short8;
typedef __attribute__((ext_vector_type(4))) float f32x4;
typedef __attribute__((ext_vector_type(4))) unsigned int u32x4;
typedef __attribute__((ext_vector_type(2))) unsigned int u32x2;

__device__ __forceinline__ unsigned short f2bf(float f) {
    unsigned int u = __float_as_uint(f);
    u = (u + 0x7FFFu + ((u >> 16) & 1u)) >> 16;
    return (unsigned short)u;
}
__device__ __forceinline__ float bf2f(unsigned int s) {
    return __uint_as_float(s << 16);
}
__device__ __forceinline__ float rmax16(float v) {
    v = fmaxf(v, __shfl_xor(v, 1));
    v = fmaxf(v, __shfl_xor(v, 2));
    v = fmaxf(v, __shfl_xor(v, 4));
    v = fmaxf(v, __shfl_xor(v, 8));
    return v;
}
__device__ __forceinline__ float rsum16(float v) {
    v += __shfl_xor(v, 1);
    v += __shfl_xor(v, 2);
    v += __shfl_xor(v, 4);
    v += __shfl_xor(v, 8);
    return v;
}
// split-bf16 hi/lo pack of 8 floats -> two bf16x8 fragments
__device__ __forceinline__ void pack_hilo(const float* v, u32x4& hi, u32x4& lo) {
    #pragma unroll
    for (int p = 0; p < 4; ++p) {
        unsigned int h0 = f2bf(v[2 * p]), h1 = f2bf(v[2 * p + 1]);
        float l0 = v[2 * p] - bf2f(h0), l1 = v[2 * p + 1] - bf2f(h1);
        hi[p] = h0 | (h1 << 16);
        lo[p] = (unsigned int)f2bf(l0) | ((unsigned int)f2bf(l1) << 16);
    }
}

// ---------------------------------------------------------------------------
// K0: strength projection, once (1 block).
// ---------------------------------------------------------------------------
__global__ __launch_bounds__(256) void k_sv(
    const float* __restrict__ strength, const float* __restrict__ str_w,
    const float* __restrict__ str_b, float* __restrict__ sv)
{
    __shared__ float part_s[4][64];
    const int c = threadIdx.x & 63, pr = threadIdx.x >> 6;
    const float* wrow = str_w + c * 512 + pr * 128;
    const float* st   = strength + pr * 128;
    float acc = 0.f;
    #pragma unroll
    for (int j4 = 0; j4 < 32; ++j4) {
        f32x4 wv = *(const f32x4*)(wrow + j4 * 4);
        f32x4 s4 = *(const f32x4*)(st + j4 * 4);
        acc += wv[0] * s4[0] + wv[1] * s4[1] + wv[2] * s4[2] + wv[3] * s4[3];
    }
    part_s[pr][c] = acc;
    __syncthreads();
    if (threadIdx.x < 64)
        sv[threadIdx.x] = part_s[0][threadIdx.x] + part_s[1][threadIdx.x]
                        + part_s[2][threadIdx.x] + part_s[3][threadIdx.x]
                        + str_b[threadIdx.x];
}

// ---------------------------------------------------------------------------
// K1: QKV projection as MFMA GEMM (split-bf16, no LDS, no transpose).
// ---------------------------------------------------------------------------
__global__ __launch_bounds__(256) void k_qkv(
    const float* __restrict__ x, const int* __restrict__ embed_id,
    const float* __restrict__ qw, const float* __restrict__ kw,
    const float* __restrict__ vw, const float* __restrict__ sv,
    unsigned short* __restrict__ yq, unsigned short* __restrict__ yk,
    unsigned short* __restrict__ yv)
{
    const int tid  = threadIdx.x;
    const int wv   = tid >> 6;
    const int lane = tid & 63;
    const int quad = lane >> 4;
    const int l15  = lane & 15;
    const int r0   = blockIdx.x * 64 + wv * 16;   // 16 rows for this wave
    const int b    = r0 >> 13;
    const int rloc = (r0 & 8191) + l15;           // row within batch
    const float* xb = x + (size_t)b * 524288;
    const int id = embed_id[0];

    // B fragments (x^T), hi/lo split.  B[n=l15][k=quad*8+j]
    u32x4 bhi[2], blo[2];
    #pragma unroll
    for (int kc = 0; kc < 2; ++kc) {
        float xv[8];
        #pragma unroll
        for (int j = 0; j < 8; ++j)
            xv[j] = xb[(kc * 32 + quad * 8 + j) * 8192 + rloc];
        pack_hilo(xv, bhi[kc], blo[kc]);
    }

    f32x4 svr[4];
    #pragma unroll
    for (int mt = 0; mt < 4; ++mt)
        svr[mt] = *(const f32x4*)(sv + mt * 16 + quad * 4);

    const float SCALE = 0.08838834764831845f;  // 1/sqrt(128)

    for (int mat = 0; mat < 3; ++mat) {
        const float* em = (mat == 0 ? qw : mat == 1 ? kw : vw) + id * 4096;
        u32x4 ahi[4][2], alo[4][2];
        #pragma unroll
        for (int mt = 0; mt < 4; ++mt)
            #pragma unroll
            for (int kc = 0; kc < 2; ++kc) {
                const float* src = em + (mt * 16 + l15) * 64 + kc * 32 + quad * 8;
                f32x4 e0 = *(const f32x4*)src;
                f32x4 e1 = *(const f32x4*)(src + 4);
                float ev[8] = {e0[0], e0[1], e0[2], e0[3], e1[0], e1[1], e1[2], e1[3]};
                pack_hilo(ev, ahi[mt][kc], alo[mt][kc]);
            }

        f32x4 acc[4] = {};
        #pragma unroll
        for (int kc = 0; kc < 2; ++kc)
            #pragma unroll
            for (int mt = 0; mt < 4; ++mt) {
                acc[mt] = __builtin_amdgcn_mfma_f32_16x16x32_bf16(
                    __builtin_bit_cast(short8, ahi[mt][kc]),
                    __builtin_bit_cast(short8, bhi[kc]), acc[mt], 0, 0, 0);
                acc[mt] = __builtin_amdgcn_mfma_f32_16x16x32_bf16(
                    __builtin_bit_cast(short8, ahi[mt][kc]),
                    __builtin_bit_cast(short8, blo[kc]), acc[mt], 0, 0, 0);
                acc[mt] = __builtin_amdgcn_mfma_f32_16x16x32_bf16(
                    __builtin_bit_cast(short8, alo[mt][kc]),
                    __builtin_bit_cast(short8, bhi[kc]), acc[mt], 0, 0, 0);
            }

        unsigned short* y = (mat == 0 ? yq : mat == 1 ? yk : yv);
        #pragma unroll
        for (int mt = 0; mt < 4; ++mt) {
            float v0 = acc[mt][0] + svr[mt][0];
            float v1 = acc[mt][1] + svr[mt][1];
            float v2 = acc[mt][2] + svr[mt][2];
            float v3 = acc[mt][3] + svr[mt][3];
            if (mat == 0) { v0 *= SCALE; v1 *= SCALE; v2 *= SCALE; v3 *= SCALE; }
            u32x2 pk;
            pk[0] = (unsigned int)f2bf(v0) | ((unsigned int)f2bf(v1) << 16);
            pk[1] = (unsigned int)f2bf(v2) | ((unsigned int)f2bf(v3) << 16);
            *(u32x2*)(y + (size_t)(r0 + l15) * 64 + mt * 16 + quad * 4) = pk;
        }
    }
}

// ---------------------------------------------------------------------------
// K2: transpose V -> yvT[bh][d][t]  (bf16), 64x64 tiles through LDS.
// ---------------------------------------------------------------------------
__global__ __launch_bounds__(256) void k_vtrans(
    const unsigned short* __restrict__ yv, unsigned short* __restrict__ yvT)
{
    __shared__ unsigned short t_s[64 * 66];
    const int blk = blockIdx.x;
    const int bh = blk >> 5;
    const int dt = (blk >> 4) & 1;
    const int tt = blk & 15;
    const int b = bh >> 2, h = bh & 3;
    const int t0 = tt * 64, d0 = dt * 64;
    const unsigned int* src = (const unsigned int*)yv;
    for (int p = 0; p < 8; ++p) {
        int flat = p * 256 + threadIdx.x;
        int tr = flat >> 5, dp = flat & 31;
        unsigned int u = src[(b * S_ + t0 + tr) * 256 + (h * HD + d0) / 2 + dp];
        t_s[(2 * dp) * 66 + tr]     = (unsigned short)(u & 0xFFFFu);
        t_s[(2 * dp + 1) * 66 + tr] = (unsigned short)(u >> 16);
    }
    __syncthreads();
    unsigned int* dst = (unsigned int*)yvT;
    for (int p = 0; p < 8; ++p) {
        int flat = p * 256 + threadIdx.x;
        int dr = flat >> 5, tp = flat & 31;
        unsigned int lo = t_s[dr * 66 + 2 * tp];
        unsigned int hi = t_s[dr * 66 + 2 * tp + 1];
        dst[(bh * HD + d0 + dr) * (S_ / 2) + t0 / 2 + tp] = lo | (hi << 16);
    }
}

// ---------------------------------------------------------------------------
// K3: pos-attention collapsed branch.  pos_attn rows are s-independent =>
// vbar[bh][d] = sum_t softmax_t(-A[t]) * V[t][d].  One block per bh.
// ---------------------------------------------------------------------------
__global__ __launch_bounds__(256) void k_vbar(
    const unsigned short* __restrict__ yvT, const float* __restrict__ pos,
    const float* __restrict__ pw1, const float* __restrict__ pb1,
    const float* __restrict__ pw2, const float* __restrict__ pb2,
    const float* __restrict__ head_w, float* __restrict__ vbar_g)
{
    __shared__ float p_s[1024];
    __shared__ float red_s[4];
    __shared__ float stat_s;
    const int tid = threadIdx.x, wv = tid >> 6;
    const int bh = blockIdx.x, b = bh >> 2, h = bh & 3;

    float w1_[9], b1_[3], w2_[24], b2_[8], hw_[8];
    #pragma unroll
    for (int i = 0; i < 9; ++i)  w1_[i] = pw1[i];
    #pragma unroll
    for (int i = 0; i < 3; ++i)  b1_[i] = pb1[i];
    #pragma unroll
    for (int i = 0; i < 24; ++i) w2_[i] = pw2[i];
    #pragma unroll
    for (int i = 0; i < 8; ++i)  b2_[i] = pb2[i];
    #pragma unroll
    for (int i = 0; i < 8; ++i)  hw_[i] = head_w[h * 8 + i];

    float lmax = -INFINITY;
    #pragma unroll
    for (int k = 0; k < 4; ++k) {
        const int t = k * 256 + tid;
        float p0 = pos[(b * S_ + t) * 3 + 0];
        float p1 = pos[(b * S_ + t) * 3 + 1];
        float p2 = pos[(b * S_ + t) * 3 + 2];
        float h0 = fmaxf(0.f, p0 * w1_[0] + p1 * w1_[1] + p2 * w1_[2] + b1_[0]);
        float h1 = fmaxf(0.f, p0 * w1_[3] + p1 * w1_[4] + p2 * w1_[5] + b1_[1]);
        float h2 = fmaxf(0.f, p0 * w1_[6] + p1 * w1_[7] + p2 * w1_[8] + b1_[2]);
        float A = 0.f;
        #pragma unroll
        for (int o8 = 0; o8 < 8; ++o8) {
            float ph = h0 * w2_[o8 * 3] + h1 * w2_[o8 * 3 + 1] + h2 * w2_[o8 * 3 + 2] + b2_[o8];
            A += ph * hw_[o8];
        }
        p_s[t] = -A;
        lmax = fmaxf(lmax, -A);
    }
    #pragma unroll
    for (int off = 1; off < 64; off <<= 1)
        lmax = fmaxf(lmax, __shfl_xor(lmax, off));
    if ((tid & 63) == 0) red_s[wv] = lmax;
    __syncthreads();
    const float bmax = fmaxf(fmaxf(red_s[0], red_s[1]), fmaxf(red_s[2], red_s[3]));
    __syncthreads();
    float lsum = 0.f;
    #pragma unroll
    for (int k = 0; k < 4; ++k) {
        const int t = k * 256 + tid;
        float e = __expf(p_s[t] - bmax);
        p_s[t] = e;
        lsum += e;
    }
    #pragma unroll
    for (int off = 1; off < 64; off <<= 1)
        lsum += __shfl_xor(lsum, off);
    if ((tid & 63) == 0) red_s[wv] = lsum;
    __syncthreads();
    if (tid == 0) stat_s = 1.f / (red_s[0] + red_s[1] + red_s[2] + red_s[3]);
    __syncthreads();
    const float inv = stat_s;

    const int d = tid >> 1, th = (tid & 1) * 512;
    const unsigned short* vrow = yvT + (size_t)(bh * HD + d) * S_ + th;
    float acc = 0.f;
    #pragma unroll 8
    for (int i = 0; i < 64; ++i) {
        u32x4 v = *(const u32x4*)(vrow + i * 8);
        const float* pp = p_s + th + i * 8;
        acc += pp[0] * bf2f(v[0] & 0xFFFFu) + pp[1] * bf2f(v[0] >> 16)
             + pp[2] * bf2f(v[1] & 0xFFFFu) + pp[3] * bf2f(v[1] >> 16)
             + pp[4] * bf2f(v[2] & 0xFFFFu) + pp[5] * bf2f(v[2] >> 16)
             + pp[6] * bf2f(v[3] & 0xFFFFu) + pp[7] * bf2f(v[3] >> 16);
    }
    acc += __shfl_xor(acc, 1);
    if ((tid & 1) == 0) vbar_g[bh * HD + d] = acc * inv;
}

// ---------------------------------------------------------------------------
// K4: flash attention, fully wave-local softmax.  1 wave per block, grid 1024:
// blk -> bh = blk&15 (2 bh per XCD for L2 locality), qt = blk>>4 (16 Q-rows).
// K frags double-buffered in registers; V issued before the softmax chain.
// P transposes C->A layout via 1.25KB wave-private LDS (stride 40 shorts).
// Epilogue: gate-combine with precomputed vbar.  No cross-wave traffic.
// ---------------------------------------------------------------------------
__global__ __launch_bounds__(64) void k_attn(
    const unsigned short* __restrict__ yq, const unsigned short* __restrict__ yk,
    const unsigned short* __restrict__ yvT, const float* __restrict__ vbar_g,
    const float* __restrict__ gate, float* __restrict__ out)
{
    __shared__ __align__(16) unsigned short p_s[16 * 40];
    const int lane = threadIdx.x;
    const int quad = lane >> 4;
    const int l15  = lane & 15;
    const int bh = blockIdx.x & 15, qt = blockIdx.x >> 4;
    const int b = bh >> 2, h = bh & 3;
    const int s0 = qt * 16;

    // Q fragments (A-layout), register-resident
    u32x4 qf[4];
    #pragma unroll
    for (int kc = 0; kc < 4; ++kc)
        qf[kc] = *(const u32x4*)(yq +
            (size_t)(b * S_ + s0 + l15) * F_ + h * HD + kc * 32 + quad * 8);

    f32x4 o[8] = {};
    float m_[4] = {-INFINITY, -INFINITY, -INFINITY, -INFINITY};
    float l_[4] = {0.f, 0.f, 0.f, 0.f};

    // K double buffer: frag (nt,kc) = kf[buf][nt*4+kc]
    u32x4 kf[2][8];
    #pragma unroll
    for (int nt = 0; nt < 2; ++nt)
        #pragma unroll
        for (int kc = 0; kc < 4; ++kc)
            kf[0][nt * 4 + kc] = *(const u32x4*)(yk +
                (size_t)(b * S_ + nt * 16 + l15) * F_ + h * HD + kc * 32 + quad * 8);

    #pragma unroll 2
    for (int tt = 0; tt < 32; ++tt) {
        const int cur = tt & 1;
        const int t0 = tt * 32;

        // V loads issued early; consumed after softmax (latency hidden)
        u32x4 vf[8];
        #pragma unroll
        for (int nt = 0; nt < 8; ++nt)
            vf[nt] = *(const u32x4*)(yvT +
                (size_t)(bh * HD + nt * 16 + l15) * S_ + t0 + quad * 8);

        // S = Q K^T
        f32x4 sacc[2] = {};
        #pragma unroll
        for (int kc = 0; kc < 4; ++kc)
            #pragma unroll
            for (int nt = 0; nt < 2; ++nt)
                sacc[nt] = __builtin_amdgcn_mfma_f32_16x16x32_bf16(
                    __builtin_bit_cast(short8, qf[kc]),
                    __builtin_bit_cast(short8, kf[cur][nt * 4 + kc]), sacc[nt], 0, 0, 0);

        // K prefetch for next tile
        if (tt < 31) {
            const int t0n = t0 + 32;
            #pragma unroll
            for (int nt = 0; nt < 2; ++nt)
                #pragma unroll
                for (int kc = 0; kc < 4; ++kc)
                    kf[cur ^ 1][nt * 4 + kc] = *(const u32x4*)(yk +
                        (size_t)(b * S_ + t0n + nt * 16 + l15) * F_ + h * HD + kc * 32 + quad * 8);
        }

        // wave-local online softmax (rows = quad*4+r, stats in registers)
        float alpha[4], p0[4], p1[4];
        #pragma unroll
        for (int r = 0; r < 4; ++r) {
            float mx = rmax16(fmaxf(sacc[0][r], sacc[1][r]));
            float mn = fmaxf(m_[r], mx);
            alpha[r] = __expf(m_[r] - mn);
            m_[r] = mn;
            p0[r] = __expf(sacc[0][r] - mn);
            p1[r] = __expf(sacc[1][r] - mn);
            l_[r] = l_[r] * alpha[r] + rsum16(p0[r] + p1[r]);
        }
        #pragma unroll
        for (int nt = 0; nt < 8; ++nt)
            #pragma unroll
            for (int r = 0; r < 4; ++r)
                o[nt][r] *= alpha[r];

        // P: C-layout -> LDS -> A-layout (wave-private; barrier is 1-wave cheap)
        #pragma unroll
        for (int r = 0; r < 4; ++r) {
            p_s[(quad * 4 + r) * 40 + l15]      = f2bf(p0[r]);
            p_s[(quad * 4 + r) * 40 + 16 + l15] = f2bf(p1[r]);
        }
        __syncthreads();
        u32x4 pA = *(const u32x4*)&p_s[l15 * 40 + quad * 8];
        __syncthreads();

        // O += P V
        #pragma unroll
        for (int nt = 0; nt < 8; ++nt)
            o[nt] = __builtin_amdgcn_mfma_f32_16x16x32_bf16(
                __builtin_bit_cast(short8, pA),
                __builtin_bit_cast(short8, vf[nt]), o[nt], 0, 0, 0);
    }

    // epilogue: normalize + gate-combine with vbar
    const float gf = 1.f / (1.f + __expf(-gate[h]));
    float invl[4];
    #pragma unroll
    for (int r = 0; r < 4; ++r) invl[r] = 1.f / l_[r];
    #pragma unroll
    for (int nt = 0; nt < 8; ++nt) {
        const float vb = gf * vbar_g[bh * HD + nt * 16 + l15];
        #pragma unroll
        for (int r = 0; r < 4; ++r) {
            float y = (1.f - gf) * (o[nt][r] * invl[r]) + vb;
            out[(size_t)(b * S_ + s0 + quad * 4 + r) * F_ + h * HD + nt * 16 + l15] = y;
        }
    }
}

// ---------------------------------------------------------------------------
// K5: output projection as MFMA (split-bf16), in-place on d_out.
// Wave owns 16 rows exclusively: loads before stores => in-place safe.
// ---------------------------------------------------------------------------
__global__ __launch_bounds__(256) void k_oproj(
    float* __restrict__ out, const float* __restrict__ ow,
    const float* __restrict__ ob)
{
    const int tid  = threadIdx.x;
    const int wv   = tid >> 6;
    const int lane = tid & 63;
    const int quad = lane >> 4;
    const int l15  = lane & 15;
    const int r0   = blockIdx.x * 64 + wv * 16;

    // B fragments from Y rows (hi/lo split)
    u32x4 bhi[2], blo[2];
    #pragma unroll
    for (int kc = 0; kc < 2; ++kc) {
        const float* src = out + (size_t)(r0 + l15) * 64 + kc * 32 + quad * 8;
        f32x4 y0 = *(const f32x4*)src;
        f32x4 y1 = *(const f32x4*)(src + 4);
        float yv8[8] = {y0[0], y0[1], y0[2], y0[3], y1[0], y1[1], y1[2], y1[3]};
        pack_hilo(yv8, bhi[kc], blo[kc]);
    }
    // A fragments from out_w
    u32x4 ahi[4][2], alo[4][2];
    #pragma unroll
    for (int mt = 0; mt < 4; ++mt)
        #pragma unroll
        for (int kc = 0; kc < 2; ++kc) {
            const float* src = ow + (mt * 16 + l15) * 64 + kc * 32 + quad * 8;
            f32x4 e0 = *(const f32x4*)src;
            f32x4 e1 = *(const f32x4*)(src + 4);
            float ev[8] = {e0[0], e0[1], e0[2], e0[3], e1[0], e1[1], e1[2], e1[3]};
            pack_hilo(ev, ahi[mt][kc], alo[mt][kc]);
        }

    f32x4 acc[4] = {};
    #pragma unroll
    for (int kc = 0; kc < 2; ++kc)
        #pragma unroll
        for (int mt = 0; mt < 4; ++mt) {
            acc[mt] = __builtin_amdgcn_mfma_f32_16x16x32_bf16(
                __builtin_bit_cast(short8, ahi[mt][kc]),
                __builtin_bit_cast(short8, bhi[kc]), acc[mt], 0, 0, 0);
            acc[mt] = __builtin_amdgcn_mfma_f32_16x16x32_bf16(
                __builtin_bit_cast(short8, ahi[mt][kc]),
                __builtin_bit_cast(short8, blo[kc]), acc[mt], 0, 0, 0);
            acc[mt] = __builtin_amdgcn_mfma_f32_16x16x32_bf16(
                __builtin_bit_cast(short8, alo[mt][kc]),
                __builtin_bit_cast(short8, bhi[kc]), acc[mt], 0, 0, 0);
        }

    #pragma unroll
    for (int mt = 0; mt < 4; ++mt) {
        f32x4 bias = *(const f32x4*)(ob + mt * 16 + quad * 4);
        f32x4 v = acc[mt] + bias;
        *(f32x4*)(out + (size_t)(r0 + l15) * 64 + mt * 16 + quad * 4) = v;
    }
}

extern "C" void kernel_launch(void* const* d_in, const int* in_sizes, int n_in,
                              void* d_out, int out_size, void* d_ws, size_t ws_size,
                              hipStream_t stream) {
    (void)in_sizes; (void)n_in; (void)out_size; (void)ws_size;
    const float* x        = (const float*)d_in[0];
    const float* pos      = (const float*)d_in[1];
    const float* strength = (const float*)d_in[2];
    const int*   embed_id = (const int*)d_in[3];
    const float* qw       = (const float*)d_in[4];
    const float* kw       = (const float*)d_in[5];
    const float* vw       = (const float*)d_in[6];
    const float* pw1      = (const float*)d_in[7];
    const float* pb1      = (const float*)d_in[8];
    const float* pw2      = (const float*)d_in[9];
    const float* pb2      = (const float*)d_in[10];
    const float* head_w   = (const float*)d_in[11];
    const float* gate     = (const float*)d_in[13];
    const float* out_w    = (const float*)d_in[14];
    const float* out_b    = (const float*)d_in[15];
    const float* str_w    = (const float*)d_in[16];
    const float* str_b    = (const float*)d_in[17];
    float* out = (float*)d_out;

    unsigned short* yq  = (unsigned short*)d_ws;
    unsigned short* yk  = yq + 2097152;
    unsigned short* yv  = yk + 2097152;
    unsigned short* yvT = yv + 2097152;   // total 16 MiB of workspace
    // sv parks in yvT region (consumed by k_qkv before k_vtrans writes yvT);
    // vbar parks in yv region (yv dead after k_vtrans).
    float* sv     = (float*)yvT;
    float* vbar_g = (float*)yv;

    k_sv<<<1, 256, 0, stream>>>(strength, str_w, str_b, sv);
    k_qkv<<<512, 256, 0, stream>>>(x, embed_id, qw, kw, vw, sv, yq, yk, yv);
    k_vtrans<<<512, 256, 0, stream>>>(yv, yvT);
    k_vbar<<<16, 256, 0, stream>>>(yvT, pos, pw1, pb1, pw2, pb2, head_w, vbar_g);
    k_attn<<<1024, 64, 0, stream>>>(yq, yk, yvT, vbar_g, gate, out);
    k_oproj<<<512, 256, 0, stream>>>(out, out_w, out_b);
}